// Round 5
// baseline (454.044 us; speedup 1.0000x reference)
//
#include <hip/hip_runtime.h>
#include <hip/hip_bf16.h>

typedef __bf16 bf16;
typedef unsigned int u32;
typedef __attribute__((ext_vector_type(8))) __bf16 bf16x8;
typedef __attribute__((ext_vector_type(4))) float f32x4;

#define Bsz 256
#define Tsz 256
#define Csz 384
#define Hn  6
#define Dh  64
#define NQKV 1152   // 3 mats * 6 heads * 64

#define MFMA16(a, b, c) __builtin_amdgcn_mfma_f32_16x16x32_bf16(a, b, c, 0, 0, 0)

typedef __attribute__((address_space(3))) u32 lds_u32;
typedef __attribute__((address_space(1))) const u32 gbl_u32;
__device__ __forceinline__ void gl2lds16(const void* g, void* l) {
    // async global->LDS, 16B/lane; LDS dest = wave-uniform base + lane*16
    __builtin_amdgcn_global_load_lds((gbl_u32*)g, (lds_u32*)l, 16, 0, 0);
}

__device__ __forceinline__ float redmax16(float x) {
    x = fmaxf(x, __shfl_xor(x, 1));
    x = fmaxf(x, __shfl_xor(x, 2));
    x = fmaxf(x, __shfl_xor(x, 4));
    x = fmaxf(x, __shfl_xor(x, 8));
    return x;
}
__device__ __forceinline__ float redsum16(float x) {
    x += __shfl_xor(x, 1);
    x += __shfl_xor(x, 2);
    x += __shfl_xor(x, 4);
    x += __shfl_xor(x, 8);
    return x;
}

// ---------------- x: fp32 -> bf16 ----------------
__global__ __launch_bounds__(256) void convert_x(
    const float* __restrict__ x, bf16* __restrict__ xb)
{
    size_t i = ((size_t)blockIdx.x * 256 + threadIdx.x) * 8;
    float4 f0 = *(const float4*)&x[i];
    float4 f1 = *(const float4*)&x[i + 4];
    bf16x8 o;
    o[0] = (bf16)f0.x; o[1] = (bf16)f0.y; o[2] = (bf16)f0.z; o[3] = (bf16)f0.w;
    o[4] = (bf16)f1.x; o[5] = (bf16)f1.y; o[6] = (bf16)f1.z; o[7] = (bf16)f1.w;
    *(bf16x8*)&xb[i] = o;
}

// ---------------- weights: fp32 -> bf16, B^T [n][k] layout ----------------
__global__ __launch_bounds__(384) void prep_w(
    const float* __restrict__ Wq, const float* __restrict__ Wk,
    const float* __restrict__ Wv, const float* __restrict__ Wp,
    bf16* __restrict__ Btqkv, bf16* __restrict__ Bpt)
{
    const int n = blockIdx.x, k = threadIdx.x;
    if (n < NQKV) {
        int wi = n / Csz, rem = n - wi * Csz, h = rem >> 6, d = rem & 63;
        const float* W = wi == 0 ? Wq : (wi == 1 ? Wk : Wv);
        Btqkv[(size_t)n * Csz + k] = (bf16)W[((size_t)h * Csz + k) * Dh + d];
    } else {
        int n2 = n - NQKV;
        Bpt[(size_t)n2 * Csz + k] = (bf16)Wp[(size_t)k * Csz + n2];
    }
}

// ======================================================================
// Persistent pipelined GEMM: grid = 256 blocks (1/CU), each block owns one
// 256-row A-panel (m-tile) and sweeps ALL n-tiles x 6 K-tiles as ONE
// continuous ring-2 counted-vmcnt pipeline (54 stages for qkv, 18 for proj).
// Prologue/drain paid once per block instead of once per (m,n) tile; A-panel
// reuse is block-private L2. Per-n epilogue: snapshot acc->oacc and issue
// the scattered stores ONE TILE LATER (after the next barrier) so they drain
// under a full compute phase and never stall the vmcnt(6) discipline
// (vmcnt counts stores too). Buffer parity = kc&1 (6 is even).
// 8 waves (512 thr), wave tile 64x64 (4M x 2N), 96 KiB LDS, T2 XOR-swizzle,
// T5 setprio.
// ======================================================================

__device__ __forceinline__ void stage_tile512(
    const char* Ab, const char* Bb, int m0, int n0, int t,
    char* AsB, char* BsB, int tid)
{
    const int srow = tid >> 3;                                   // 0..63
    const int scs  = ((tid & 7) * 16) ^ ((srow & 7) << 4);       // inv-swizzled col byte
    #pragma unroll
    for (int j = 0; j < 4; ++j)   // A: 256 rows x 128B
        gl2lds16(Ab + (size_t)(m0 + j * 64 + srow) * 768 + t * 128 + scs,
                 AsB + j * 8192 + tid * 16);
    #pragma unroll
    for (int j = 0; j < 2; ++j)   // B: 128 rows x 128B
        gl2lds16(Bb + (size_t)(n0 + j * 64 + srow) * 768 + t * 128 + scs,
                 BsB + j * 8192 + tid * 16);
}

__device__ __forceinline__ void compute_tile512(
    const char* Ap, const char* Bp,
    int wm4, int wn2, int l4, int quad, f32x4 acc[4][4])
{
    const int cswz = (l4 & 7) << 4;
    bf16x8 bfr[4][2], af[4][2];
    #pragma unroll
    for (int fn = 0; fn < 4; ++fn)
        #pragma unroll
        for (int ks = 0; ks < 2; ++ks)
            bfr[fn][ks] = *(const bf16x8*)(Bp + (wn2 * 64 + fn * 16 + l4) * 128 +
                                           ((ks * 64 + quad * 16) ^ cswz));
    #pragma unroll
    for (int fr = 0; fr < 4; ++fr)
        #pragma unroll
        for (int ks = 0; ks < 2; ++ks)
            af[fr][ks] = *(const bf16x8*)(Ap + (wm4 * 64 + fr * 16 + l4) * 128 +
                                          ((ks * 64 + quad * 16) ^ cswz));
    __builtin_amdgcn_s_setprio(1);
    #pragma unroll
    for (int ks = 0; ks < 2; ++ks)
        #pragma unroll
        for (int fr = 0; fr < 4; ++fr)
            #pragma unroll
            for (int fn = 0; fn < 4; ++fn)
                acc[fr][fn] = MFMA16(af[fr][ks], bfr[fn][ks], acc[fr][fn]);
    __builtin_amdgcn_s_setprio(0);
}

__device__ __forceinline__ void qkv_store(
    const f32x4 (&a)[4][4], int nn, int m0, int wm4, int wn2, int l4, int quad,
    bf16* __restrict__ q, bf16* __restrict__ k, bf16* __restrict__ v)
{
    #pragma unroll
    for (int fn = 0; fn < 4; ++fn) {
        int n = nn * 128 + wn2 * 64 + fn * 16 + l4;
        int wi = n / Csz, rem = n - wi * Csz;
        int h = rem >> 6, d = rem & 63;
        bf16* outp = wi == 0 ? q : (wi == 1 ? k : v);
        #pragma unroll
        for (int fr = 0; fr < 4; ++fr)
            #pragma unroll
            for (int r = 0; r < 4; ++r) {
                int m = m0 + wm4 * 64 + fr * 16 + quad * 4 + r;
                int b = m >> 8, tt = m & 255;
                outp[(((size_t)(b * Hn + h)) * Tsz + tt) * Dh + d] = (bf16)a[fr][fn][r];
            }
    }
}

// ---------------- QKV: 65536x1152x384, persistent (9 n-tiles/block) -------
__global__ __launch_bounds__(512, 2) void qkv_gemm(
    const bf16* __restrict__ A, const bf16* __restrict__ Bt,
    bf16* __restrict__ q, bf16* __restrict__ k, bf16* __restrict__ v)
{
    __shared__ bf16 As[2][256][64];
    __shared__ bf16 Bs[2][128][64];
    char* As0 = (char*)&As[0][0][0]; char* As1 = (char*)&As[1][0][0];
    char* Bs0 = (char*)&Bs[0][0][0]; char* Bs1 = (char*)&Bs[1][0][0];
    const int tid = threadIdx.x, w = tid >> 6, lane = tid & 63;
    const int l4 = lane & 15, quad = lane >> 4;
    const int wm4 = w >> 1, wn2 = w & 1;
    const int m0 = blockIdx.x * 256;

    const char* Ab = (const char*)A;
    const char* Bb = (const char*)Bt;
    f32x4 acc[4][4] = {};
    f32x4 oacc[4][4];

    stage_tile512(Ab, Bb, m0, 0, 0, As0, Bs0, tid);   // s = 0
    #pragma unroll 1
    for (int n = 0; n < 9; ++n) {
        #pragma unroll
        for (int kc = 0; kc < 6; ++kc) {
            const bool last = (n == 8) && (kc == 5);
            if (!last) {
                const int n1  = (kc == 5) ? n + 1 : n;
                const int kc1 = (kc == 5) ? 0 : kc + 1;
                stage_tile512(Ab, Bb, m0, n1 * 128, kc1,
                              (kc & 1) ? As0 : As1, (kc & 1) ? Bs0 : Bs1, tid);
                asm volatile("s_waitcnt vmcnt(6)" ::: "memory");
            } else {
                asm volatile("s_waitcnt vmcnt(0)" ::: "memory");
            }
            __builtin_amdgcn_s_barrier();
            if (kc == 0 && n > 0)   // deferred epilogue: drains under this compute
                qkv_store(oacc, n - 1, m0, wm4, wn2, l4, quad, q, k, v);
            compute_tile512((kc & 1) ? As1 : As0, (kc & 1) ? Bs1 : Bs0,
                            wm4, wn2, l4, quad, acc);
            __builtin_amdgcn_s_barrier();
        }
        if (n < 8) {
            #pragma unroll
            for (int i = 0; i < 4; ++i)
                #pragma unroll
                for (int j = 0; j < 4; ++j) {
                    oacc[i][j] = acc[i][j];
                    acc[i][j] = f32x4{0, 0, 0, 0};
                }
        }
    }
    qkv_store(acc, 8, m0, wm4, wn2, l4, quad, q, k, v);
}

// ---------------- proj: 65536x384x384, persistent (3 n-tiles/block) -------
__global__ __launch_bounds__(512, 2) void proj_gemm(
    const bf16* __restrict__ A, const bf16* __restrict__ Bt,
    const float* __restrict__ bias, float* __restrict__ out)
{
    __shared__ bf16 As[2][256][64];
    __shared__ bf16 Bs[2][128][64];
    char* As0 = (char*)&As[0][0][0]; char* As1 = (char*)&As[1][0][0];
    char* Bs0 = (char*)&Bs[0][0][0]; char* Bs1 = (char*)&Bs[1][0][0];
    const int tid = threadIdx.x, w = tid >> 6, lane = tid & 63;
    const int l4 = lane & 15, quad = lane >> 4;
    const int wm4 = w >> 1, wn2 = w & 1;
    const int m0 = blockIdx.x * 256;

    // preload bias to regs: no loads inside the pipeline (vmcnt discipline)
    float bvr[3][4];
    #pragma unroll
    for (int nn = 0; nn < 3; ++nn)
        #pragma unroll
        for (int fn = 0; fn < 4; ++fn)
            bvr[nn][fn] = bias[nn * 128 + wn2 * 64 + fn * 16 + l4];

    const char* Ab = (const char*)A;
    const char* Bb = (const char*)Bt;
    f32x4 acc[4][4] = {};
    f32x4 oacc[4][4];

    stage_tile512(Ab, Bb, m0, 0, 0, As0, Bs0, tid);
    #pragma unroll 1
    for (int n = 0; n < 3; ++n) {
        #pragma unroll
        for (int kc = 0; kc < 6; ++kc) {
            const bool last = (n == 2) && (kc == 5);
            if (!last) {
                const int n1  = (kc == 5) ? n + 1 : n;
                const int kc1 = (kc == 5) ? 0 : kc + 1;
                stage_tile512(Ab, Bb, m0, n1 * 128, kc1,
                              (kc & 1) ? As0 : As1, (kc & 1) ? Bs0 : Bs1, tid);
                asm volatile("s_waitcnt vmcnt(6)" ::: "memory");
            } else {
                asm volatile("s_waitcnt vmcnt(0)" ::: "memory");
            }
            __builtin_amdgcn_s_barrier();
            if (kc == 0 && n > 0) {
                const int np = n - 1;
                #pragma unroll
                for (int fn = 0; fn < 4; ++fn) {
                    int ncol = np * 128 + wn2 * 64 + fn * 16 + l4;
                    float bv = bvr[np][fn];
                    #pragma unroll
                    for (int fr = 0; fr < 4; ++fr)
                        #pragma unroll
                        for (int r = 0; r < 4; ++r) {
                            int m = m0 + wm4 * 64 + fr * 16 + quad * 4 + r;
                            out[(size_t)m * Csz + ncol] = oacc[fr][fn][r] + bv;
                        }
                }
            }
            compute_tile512((kc & 1) ? As1 : As0, (kc & 1) ? Bs1 : Bs0,
                            wm4, wn2, l4, quad, acc);
            __builtin_amdgcn_s_barrier();
        }
        if (n < 2) {
            #pragma unroll
            for (int i = 0; i < 4; ++i)
                #pragma unroll
                for (int j = 0; j < 4; ++j) {
                    oacc[i][j] = acc[i][j];
                    acc[i][j] = f32x4{0, 0, 0, 0};
                }
        }
    }
    #pragma unroll
    for (int fn = 0; fn < 4; ++fn) {
        int ncol = 2 * 128 + wn2 * 64 + fn * 16 + l4;
        float bv = bvr[2][fn];
        #pragma unroll
        for (int fr = 0; fr < 4; ++fr)
            #pragma unroll
            for (int r = 0; r < 4; ++r) {
                int m = m0 + wm4 * 64 + fr * 16 + quad * 4 + r;
                out[(size_t)m * Csz + ncol] = acc[fr][fn][r] + bv;
            }
    }
}

// ======================================================================
// Flash attention v2: one block per (b,h), 512 threads (8 waves).
// K (256x64) + V^T (64x256) staged in LDS ONCE, single barrier, then a
// barrier-free main loop: wave w owns Q fragments {w, 15-w} (16 rows each)
// -> every wave does exactly 5 causal kt-tiles (perfect balance).
// ======================================================================
__global__ __launch_bounds__(512, 4) void attn_mfma(
    const bf16* __restrict__ q, const bf16* __restrict__ k, const bf16* __restrict__ v,
    bf16* __restrict__ att)
{
    __shared__ bf16 Kl[256][64];     // [s][d], swizzled
    __shared__ bf16 Vt[64][256];     // [d][s], swizzled
    __shared__ bf16 Pl[8][16][64];   // per-wave [qrow][s_local], swizzled
    const float SCL = 0.18033688f;   // 0.125 * log2(e)
    const int tid = threadIdx.x, w = tid >> 6, lane = tid & 63;
    const int l4 = lane & 15, quad = lane >> 4;
    const int cswz = l4 & 7;         // row&7 == l4&7 for all fragment reads
    const int bh = blockIdx.x;
    const int b = bh / Hn, h = bh % Hn;
    const bf16* qb = q + (size_t)bh * Tsz * Dh;
    const bf16* kb = k + (size_t)bh * Tsz * Dh;
    const bf16* vb = v + (size_t)bh * Tsz * Dh;
    char* KlB = (char*)&Kl[0][0];
    char* VtB = (char*)&Vt[0][0];
    char* PlB = (char*)&Pl[w][0][0];

    // Q for both fragments up-front (L3-hit; latency hides under staging)
    bf16x8 qa[2][2];
    #pragma unroll
    for (int fi = 0; fi < 2; ++fi) {
        int g = fi ? 15 - w : w;
        qa[fi][0] = *(const bf16x8*)&qb[(g * 16 + l4) * Dh + quad * 8];
        qa[fi][1] = *(const bf16x8*)&qb[(g * 16 + l4) * Dh + 32 + quad * 8];
    }

    // ---- stage K: linear global read, swizzled LDS write
    #pragma unroll
    for (int it = 0; it < 4; ++it) {
        int c = it * 512 + tid;                  // 16B chunk, 2048 total
        int row = c >> 3, ck = c & 7;
        bf16x8 kv = *(const bf16x8*)((const char*)kb + (size_t)c * 16);
        *(bf16x8*)(KlB + row * 128 + ((ck ^ (row & 7)) << 4)) = kv;
    }
    // ---- stage V transposed: Vt[d][s], swizzled
    #pragma unroll
    for (int it = 0; it < 4; ++it) {
        int idx = it * 512 + tid;
        int s = idx & 63, g2 = idx >> 6;         // g2 0..31
        int d8 = (g2 & 7) * 8, sg = (g2 >> 3) * 64 + s;
        bf16x8 vv = *(const bf16x8*)&vb[(size_t)sg * Dh + d8];
        #pragma unroll
        for (int j = 0; j < 8; ++j) {
            int row = d8 + j;
            *(bf16*)(VtB + row * 512 + (((sg >> 3) ^ (row & 7)) << 4) + (sg & 7) * 2) = vv[j];
        }
    }
    __syncthreads();

    #pragma unroll
    for (int fi = 0; fi < 2; ++fi) {
        const int g = fi ? 15 - w : w;
        const int diag = g >> 2;
        const int tg = g * 16 + quad * 4;        // +r = output row
        f32x4 o[4] = {f32x4{0,0,0,0}, f32x4{0,0,0,0}, f32x4{0,0,0,0}, f32x4{0,0,0,0}};
        float mrun[4] = {-3.0e38f, -3.0e38f, -3.0e38f, -3.0e38f};
        float lrun[4] = {0.f, 0.f, 0.f, 0.f};

        for (int kt = 0; kt <= diag; ++kt) {
            // ---- QK^T
            f32x4 sc[4] = {f32x4{0,0,0,0}, f32x4{0,0,0,0}, f32x4{0,0,0,0}, f32x4{0,0,0,0}};
            __builtin_amdgcn_s_setprio(1);
            #pragma unroll
            for (int nt = 0; nt < 4; ++nt) {
                const char* kbase = KlB + (kt * 64 + nt * 16 + l4) * 128;
                bf16x8 b0 = *(const bf16x8*)(kbase + ((quad ^ cswz) << 4));
                bf16x8 b1 = *(const bf16x8*)(kbase + (((4 + quad) ^ cswz) << 4));
                sc[nt] = MFMA16(qa[fi][0], b0, sc[nt]);
                sc[nt] = MFMA16(qa[fi][1], b1, sc[nt]);
            }
            __builtin_amdgcn_s_setprio(0);

            // ---- online softmax (mask only on diagonal tile)
            const bool isdiag = (kt == diag);
            float mnew[4], alpha[4];
            #pragma unroll
            for (int r = 0; r < 4; ++r) {
                float mx = mrun[r];
                #pragma unroll
                for (int nt = 0; nt < 4; ++nt) {
                    float sv = sc[nt][r] * SCL;  // log2-domain
                    if (isdiag) {
                        int sg2 = kt * 64 + nt * 16 + l4;
                        if (sg2 > tg + r) sv = -1.0e30f;
                    }
                    sc[nt][r] = sv;
                    mx = fmaxf(mx, sv);
                }
                mx = redmax16(mx);
                mnew[r] = mx;
                alpha[r] = __builtin_amdgcn_exp2f(mrun[r] - mx);
                mrun[r] = mx;
            }
            #pragma unroll
            for (int r = 0; r < 4; ++r) {
                float sm = 0.f;
                #pragma unroll
                for (int nt = 0; nt < 4; ++nt) {
                    float e = __builtin_amdgcn_exp2f(sc[nt][r] - mnew[r]);
                    sc[nt][r] = e;
                    sm += e;
                }
                sm = redsum16(sm);
                lrun[r] = lrun[r] * alpha[r] + sm;
            }
            #pragma unroll
            for (int nt = 0; nt < 4; ++nt)
                #pragma unroll
                for (int r = 0; r < 4; ++r) o[nt][r] *= alpha[r];

            // ---- P -> LDS (per-wave, swizzled)
            #pragma unroll
            for (int nt = 0; nt < 4; ++nt)
                #pragma unroll
                for (int r = 0; r < 4; ++r) {
                    int row = quad * 4 + r;
                    int colc = nt * 2 + (l4 >> 3);
                    *(bf16*)(PlB + row * 128 + ((colc ^ (row & 7)) << 4) + (l4 & 7) * 2)
                        = (bf16)sc[nt][r];
                }
            bf16x8 pa0 = *(const bf16x8*)(PlB + l4 * 128 + ((quad ^ cswz) << 4));
            bf16x8 pa1 = *(const bf16x8*)(PlB + l4 * 128 + (((4 + quad) ^ cswz) << 4));

            // ---- PV
            __builtin_amdgcn_s_setprio(1);
            #pragma unroll
            for (int nt = 0; nt < 4; ++nt) {
                const char* vbase = VtB + (nt * 16 + l4) * 512;
                bf16x8 v0 = *(const bf16x8*)(vbase + (((kt * 8 + quad) ^ cswz) << 4));
                bf16x8 v1 = *(const bf16x8*)(vbase + (((kt * 8 + 4 + quad) ^ cswz) << 4));
                o[nt] = MFMA16(pa0, v0, o[nt]);
                o[nt] = MFMA16(pa1, v1, o[nt]);
            }
            __builtin_amdgcn_s_setprio(0);
        }

        // ---- fragment epilogue
        #pragma unroll
        for (int r = 0; r < 4; ++r) {
            float inv = 1.f / lrun[r];
            #pragma unroll
            for (int nt = 0; nt < 4; ++nt)
                att[((size_t)(b * Tsz + tg + r)) * Csz + h * Dh + nt * 16 + l4] =
                    (bf16)(o[nt][r] * inv);
        }
    }
}

extern "C" void kernel_launch(void* const* d_in, const int* in_sizes, int n_in,
                              void* d_out, int out_size, void* d_ws, size_t ws_size,
                              hipStream_t stream)
{
    const float* x  = (const float*)d_in[0];
    const float* Wq = (const float*)d_in[1];
    const float* Wk = (const float*)d_in[2];
    const float* Wv = (const float*)d_in[3];
    const float* Wp = (const float*)d_in[4];
    const float* bp = (const float*)d_in[5];
    float* out = (float*)d_out;

    const size_t npe = (size_t)Bsz * Tsz * Csz;   // 25,165,824 elems
    bf16* xb    = (bf16*)d_ws;          // [65536,384]; reused as att after qkv
    bf16* att   = xb;                   // alias: xb dead once qkv_gemm completes
    bf16* q     = xb + npe;             // [B,H,T,D]
    bf16* k     = q  + npe;
    bf16* v     = k  + npe;
    bf16* Btqkv = v  + npe;             // [1152,384]
    bf16* Bpt   = Btqkv + (size_t)NQKV * Csz;   // [384,384]

    convert_x<<<npe / 2048, 256, 0, stream>>>(x, xb);
    prep_w<<<NQKV + Csz, 384, 0, stream>>>(Wq, Wk, Wv, Wp, Btqkv, Bpt);
    qkv_gemm<<<Bsz * Tsz / 256, 512, 0, stream>>>(xb, Btqkv, q, k, v);
    attn_mfma<<<Bsz * Hn, 512, 0, stream>>>(q, k, v, att);
    proj_gemm<<<Bsz * Tsz / 256, 512, 0, stream>>>(att, Bpt, bp, out);
}

// Round 6
// 375.051 us; speedup vs baseline: 1.2106x; 1.2106x over previous
//
#include <hip/hip_runtime.h>
#include <hip/hip_bf16.h>

typedef __bf16 bf16;
typedef unsigned int u32;
typedef __attribute__((ext_vector_type(8))) __bf16 bf16x8;
typedef __attribute__((ext_vector_type(4))) float f32x4;

#define Bsz 256
#define Tsz 256
#define Csz 384
#define Hn  6
#define Dh  64
#define NQKV 1152   // 3 mats * 6 heads * 64
#define NPAD 1280   // qkv N padded to 5*256
#define PPAD 512    // proj N padded to 2*256

#define MFMA16(a, b, c) __builtin_amdgcn_mfma_f32_16x16x32_bf16(a, b, c, 0, 0, 0)

typedef __attribute__((address_space(3))) u32 lds_u32;
typedef __attribute__((address_space(1))) const u32 gbl_u32;
__device__ __forceinline__ void gl2lds16(const void* g, void* l) {
    __builtin_amdgcn_global_load_lds((gbl_u32*)g, (lds_u32*)l, 16, 0, 0);
}

__device__ __forceinline__ float redmax16(float x) {
    x = fmaxf(x, __shfl_xor(x, 1));
    x = fmaxf(x, __shfl_xor(x, 2));
    x = fmaxf(x, __shfl_xor(x, 4));
    x = fmaxf(x, __shfl_xor(x, 8));
    return x;
}
__device__ __forceinline__ float redsum16(float x) {
    x += __shfl_xor(x, 1);
    x += __shfl_xor(x, 2);
    x += __shfl_xor(x, 4);
    x += __shfl_xor(x, 8);
    return x;
}

// ---------------- x: fp32 -> bf16 ----------------
__global__ __launch_bounds__(256) void convert_x(
    const float* __restrict__ x, bf16* __restrict__ xb)
{
    size_t i = ((size_t)blockIdx.x * 256 + threadIdx.x) * 8;
    float4 f0 = *(const float4*)&x[i];
    float4 f1 = *(const float4*)&x[i + 4];
    bf16x8 o;
    o[0] = (bf16)f0.x; o[1] = (bf16)f0.y; o[2] = (bf16)f0.z; o[3] = (bf16)f0.w;
    o[4] = (bf16)f1.x; o[5] = (bf16)f1.y; o[6] = (bf16)f1.z; o[7] = (bf16)f1.w;
    *(bf16x8*)&xb[i] = o;
}

// ---------------- weights -> bf16 B^T, with zeroed pad rows ----------------
__global__ __launch_bounds__(384) void prep_w(
    const float* __restrict__ Wq, const float* __restrict__ Wk,
    const float* __restrict__ Wv, const float* __restrict__ Wp,
    bf16* __restrict__ Btqkv, bf16* __restrict__ Bpt)
{
    const int n = blockIdx.x, k = threadIdx.x;
    if (n < NPAD) {
        bf16 vout = (bf16)0.f;
        if (n < NQKV) {
            int wi = n / Csz, rem = n - wi * Csz, h = rem >> 6, d = rem & 63;
            const float* W = wi == 0 ? Wq : (wi == 1 ? Wk : Wv);
            vout = (bf16)W[((size_t)h * Csz + k) * Dh + d];
        }
        Btqkv[(size_t)n * Csz + k] = vout;
    } else {
        int n2 = n - NPAD;   // 0..511
        Bpt[(size_t)n2 * Csz + k] =
            (n2 < Csz) ? (bf16)Wp[(size_t)k * Csz + n2] : (bf16)0.f;
    }
}

// ======================================================================
// 8-phase GEMM core (m201 template port): BM=BN=256, BK=64, 8 waves
// (2M x 4N), wave tile 128x64, acc[8][4]. LDS = 2buf x 2half x 128x64
// x {A,B} = 128 KiB -> 1 block/CU, 2 waves/SIMD.
// Per K-tile: 4 phases, each = {ds_read quadrant operands | stage 1
// half-tile (2 gl2lds) | barrier | lgkmcnt(0) | setprio(1) 16 MFMA
// setprio(0) | counted vmcnt | barrier}. Stage order Alo,Blo,Ahi,Bhi;
// wave fragments split across halves (fr0-3 in Alo, fr4-7 in Ahi; fn0-1
// in Blo, fn2-3 in Bhi) so consumption staggers: Alo,Blo@P0, Ahi@P1,
// Bhi@P2. vmcnt(4) allows the 2 newest halves in flight (verified
// phase-by-phase incl. prologue); tail tile drains 4->2->0.
// T2 XOR swizzle: linear gl2lds dest + inv-swizzled global col +
// swizzled ds_read (R2-measured zero conflicts).
// ======================================================================

__device__ __forceinline__ void stage_half(
    const char* Gb, int rowbase, int t, char* ldsDst, int tid)
{
    const int srow = tid >> 3;                               // 0..63
    const int scs  = ((tid & 7) * 16) ^ ((srow & 7) << 4);   // inv-swizzled col byte
    gl2lds16(Gb + (size_t)(rowbase + srow) * 768 + t * 128 + scs,
             ldsDst + tid * 16);
    gl2lds16(Gb + (size_t)(rowbase + 64 + srow) * 768 + t * 128 + scs,
             ldsDst + 8192 + tid * 16);
}

#define RD_FRAG(dst, base, row128, ks)                                         \
    dst = *(const bf16x8*)((base) + (row128) * 128 + ((((ks) * 64) + quad * 16) ^ csw));

// one tile = 4 phases; t compile-time (unrolled), LAST = (t==5)
#define GEMM_TILE(t)                                                           \
{                                                                              \
    const int cur = (t) & 1, nxt = cur ^ 1;                                    \
    char* Ac = As + cur * 32768; char* Bc = Bs + cur * 32768;                  \
    char* An = As + nxt * 32768; char* Bn = Bs + nxt * 32768;                  \
    bf16x8 aLo[4][2], aHi[4][2], bLo[2][2], bHi[2][2];                         \
    /* ---- P0: read Alo,Blo; stage Alo(t+1); MFMA frlo x fnlo ---- */         \
    _Pragma("unroll") for (int fr = 0; fr < 4; ++fr)                           \
        _Pragma("unroll") for (int ks = 0; ks < 2; ++ks)                       \
            RD_FRAG(aLo[fr][ks], Ac, wmw * 64 + fr * 16 + l4, ks);             \
    _Pragma("unroll") for (int fn = 0; fn < 2; ++fn)                           \
        _Pragma("unroll") for (int ks = 0; ks < 2; ++ks)                       \
            RD_FRAG(bLo[fn][ks], Bc, wnw * 32 + fn * 16 + l4, ks);             \
    if ((t) < 5) stage_half(Ab, m0, (t) + 1, An, tid);                         \
    __builtin_amdgcn_s_barrier();                                              \
    asm volatile("s_waitcnt lgkmcnt(0)" ::: "memory");                         \
    __builtin_amdgcn_s_setprio(1);                                             \
    _Pragma("unroll") for (int ks = 0; ks < 2; ++ks)                           \
        _Pragma("unroll") for (int fr = 0; fr < 4; ++fr)                       \
            _Pragma("unroll") for (int fn = 0; fn < 2; ++fn)                   \
                acc[fr][fn] = MFMA16(aLo[fr][ks], bLo[fn][ks], acc[fr][fn]);   \
    __builtin_amdgcn_s_setprio(0);                                             \
    if ((t) < 5) { asm volatile("s_waitcnt vmcnt(4)" ::: "memory"); }          \
    else         { asm volatile("s_waitcnt vmcnt(2)" ::: "memory"); }          \
    __builtin_amdgcn_s_barrier();                                              \
    /* ---- P1: read Ahi; stage Blo(t+1); MFMA frhi x fnlo ---- */             \
    _Pragma("unroll") for (int fr = 0; fr < 4; ++fr)                           \
        _Pragma("unroll") for (int ks = 0; ks < 2; ++ks)                       \
            RD_FRAG(aHi[fr][ks], Ac + 16384, wmw * 64 + fr * 16 + l4, ks);     \
    if ((t) < 5) stage_half(Bb, n0, (t) + 1, Bn, tid);                         \
    __builtin_amdgcn_s_barrier();                                              \
    asm volatile("s_waitcnt lgkmcnt(0)" ::: "memory");                         \
    __builtin_amdgcn_s_setprio(1);                                             \
    _Pragma("unroll") for (int ks = 0; ks < 2; ++ks)                           \
        _Pragma("unroll") for (int fr = 0; fr < 4; ++fr)                       \
            _Pragma("unroll") for (int fn = 0; fn < 2; ++fn)                   \
                acc[4 + fr][fn] = MFMA16(aHi[fr][ks], bLo[fn][ks], acc[4 + fr][fn]); \
    __builtin_amdgcn_s_setprio(0);                                             \
    if ((t) < 5) { asm volatile("s_waitcnt vmcnt(4)" ::: "memory"); }          \
    else         { asm volatile("s_waitcnt vmcnt(0)" ::: "memory"); }          \
    __builtin_amdgcn_s_barrier();                                              \
    /* ---- P2: read Bhi; stage Ahi(t+1); MFMA frhi x fnhi ---- */             \
    _Pragma("unroll") for (int fn = 0; fn < 2; ++fn)                           \
        _Pragma("unroll") for (int ks = 0; ks < 2; ++ks)                       \
            RD_FRAG(bHi[fn][ks], Bc + 16384, wnw * 32 + fn * 16 + l4, ks);     \
    if ((t) < 5) stage_half(Ab, m0 + 128, (t) + 1, An + 16384, tid);           \
    __builtin_amdgcn_s_barrier();                                              \
    asm volatile("s_waitcnt lgkmcnt(0)" ::: "memory");                         \
    __builtin_amdgcn_s_setprio(1);                                             \
    _Pragma("unroll") for (int ks = 0; ks < 2; ++ks)                           \
        _Pragma("unroll") for (int fr = 0; fr < 4; ++fr)                       \
            _Pragma("unroll") for (int fn = 0; fn < 2; ++fn)                   \
                acc[4 + fr][2 + fn] = MFMA16(aHi[fr][ks], bHi[fn][ks], acc[4 + fr][2 + fn]); \
    __builtin_amdgcn_s_setprio(0);                                             \
    if ((t) < 5) { asm volatile("s_waitcnt vmcnt(4)" ::: "memory"); }          \
    __builtin_amdgcn_s_barrier();                                              \
    /* ---- P3: no reads; stage Bhi(t+1); MFMA frlo x fnhi ---- */             \
    if ((t) < 5) stage_half(Bb, n0 + 128, (t) + 1, Bn + 16384, tid);           \
    __builtin_amdgcn_s_barrier();                                              \
    __builtin_amdgcn_s_setprio(1);                                             \
    _Pragma("unroll") for (int ks = 0; ks < 2; ++ks)                           \
        _Pragma("unroll") for (int fr = 0; fr < 4; ++fr)                       \
            _Pragma("unroll") for (int fn = 0; fn < 2; ++fn)                   \
                acc[fr][2 + fn] = MFMA16(aLo[fr][ks], bHi[fn][ks], acc[fr][2 + fn]); \
    __builtin_amdgcn_s_setprio(0);                                             \
    if ((t) < 5) { asm volatile("s_waitcnt vmcnt(4)" ::: "memory"); }          \
    __builtin_amdgcn_s_barrier();                                              \
}

#define GEMM8_BODY()                                                           \
    /* prologue: 4 halves of tile 0, allow newest 2 outstanding */             \
    stage_half(Ab, m0,       0, As,         tid);                              \
    stage_half(Bb, n0,       0, Bs,         tid);                              \
    stage_half(Ab, m0 + 128, 0, As + 16384, tid);                              \
    stage_half(Bb, n0 + 128, 0, Bs + 16384, tid);                              \
    asm volatile("s_waitcnt vmcnt(4)" ::: "memory");                           \
    __builtin_amdgcn_s_barrier();                                              \
    GEMM_TILE(0) GEMM_TILE(1) GEMM_TILE(2)                                     \
    GEMM_TILE(3) GEMM_TILE(4) GEMM_TILE(5)

// ---------------- QKV: 65536 x 1280(pad) x 384 ----------------
__global__ __launch_bounds__(512, 2) void qkv_gemm(
    const bf16* __restrict__ A, const bf16* __restrict__ Bt,
    bf16* __restrict__ q, bf16* __restrict__ k, bf16* __restrict__ v)
{
    __shared__ char ldsbuf[131072];
    char* As = ldsbuf;
    char* Bs = ldsbuf + 65536;
    const int tid = threadIdx.x, w = tid >> 6, lane = tid & 63;
    const int l4 = lane & 15, quad = lane >> 4;
    const int wmw = w & 1, wnw = w >> 1;
    const int csw = (l4 & 7) << 4;

    // bijective XCD swizzle, n-fastest: nwg = 1280 = 8*160
    const int orig = blockIdx.x;
    const int id = (orig & 7) * 160 + (orig >> 3);
    const int mt_ = id / 5, nt_ = id - mt_ * 5;
    const int m0 = mt_ * 256, n0 = nt_ * 256;

    const char* Ab = (const char*)A;
    const char* Bb = (const char*)Bt;
    f32x4 acc[8][4] = {};

    GEMM8_BODY();

    // epilogue: scatter n -> (wi,h,d); m -> (b,t); guard pad cols
    #pragma unroll
    for (int fn = 0; fn < 4; ++fn) {
        int n = n0 + (fn >= 2) * 128 + wnw * 32 + (fn & 1) * 16 + l4;
        if (n >= NQKV) continue;
        int wi = n / Csz, rem = n - wi * Csz;
        int h = rem >> 6, d = rem & 63;
        bf16* outp = wi == 0 ? q : (wi == 1 ? k : v);
        #pragma unroll
        for (int fr = 0; fr < 8; ++fr)
            #pragma unroll
            for (int r = 0; r < 4; ++r) {
                int m = m0 + (fr >= 4) * 128 + wmw * 64 + (fr & 3) * 16 + quad * 4 + r;
                int b = m >> 8, tt = m & 255;
                outp[(((size_t)(b * Hn + h)) * Tsz + tt) * Dh + d] = (bf16)acc[fr][fn][r];
            }
    }
}

// ---------------- proj: 65536 x 512(pad) x 384 ----------------
__global__ __launch_bounds__(512, 2) void proj_gemm(
    const bf16* __restrict__ A, const bf16* __restrict__ Bt,
    const float* __restrict__ bias, float* __restrict__ out)
{
    __shared__ char ldsbuf[131072];
    char* As = ldsbuf;
    char* Bs = ldsbuf + 65536;
    const int tid = threadIdx.x, w = tid >> 6, lane = tid & 63;
    const int l4 = lane & 15, quad = lane >> 4;
    const int wmw = w & 1, wnw = w >> 1;
    const int csw = (l4 & 7) << 4;

    // nwg = 512 = 8*64, n-fastest
    const int orig = blockIdx.x;
    const int id = (orig & 7) * 64 + (orig >> 3);
    const int mt_ = id >> 1, nt_ = id & 1;
    const int m0 = mt_ * 256, n0 = nt_ * 256;

    // bias preload (outside the vmcnt-disciplined loop; older loads drain first)
    float bv[4];
    #pragma unroll
    for (int fn = 0; fn < 4; ++fn) {
        int n = n0 + (fn >= 2) * 128 + wnw * 32 + (fn & 1) * 16 + l4;
        bv[fn] = (n < Csz) ? bias[n] : 0.f;
    }

    const char* Ab = (const char*)A;
    const char* Bb = (const char*)Bt;
    f32x4 acc[8][4] = {};

    GEMM8_BODY();

    #pragma unroll
    for (int fn = 0; fn < 4; ++fn) {
        int n = n0 + (fn >= 2) * 128 + wnw * 32 + (fn & 1) * 16 + l4;
        if (n >= Csz) continue;
        #pragma unroll
        for (int fr = 0; fr < 8; ++fr)
            #pragma unroll
            for (int r = 0; r < 4; ++r) {
                int m = m0 + (fr >= 4) * 128 + wmw * 64 + (fr & 3) * 16 + quad * 4 + r;
                out[(size_t)m * Csz + n] = acc[fr][fn][r] + bv[fn];
            }
    }
}

// ======================================================================
// Flash attention v2 (unchanged from R4): one block per (b,h), 8 waves,
// K/V^T staged once, barrier-free causal-balanced main loop.
// ======================================================================
__global__ __launch_bounds__(512, 4) void attn_mfma(
    const bf16* __restrict__ q, const bf16* __restrict__ k, const bf16* __restrict__ v,
    bf16* __restrict__ att)
{
    __shared__ bf16 Kl[256][64];     // [s][d], swizzled
    __shared__ bf16 Vt[64][256];     // [d][s], swizzled
    __shared__ bf16 Pl[8][16][64];   // per-wave [qrow][s_local], swizzled
    const float SCL = 0.18033688f;   // 0.125 * log2(e)
    const int tid = threadIdx.x, w = tid >> 6, lane = tid & 63;
    const int l4 = lane & 15, quad = lane >> 4;
    const int cswz = l4 & 7;
    const int bh = blockIdx.x;
    const int b = bh / Hn, h = bh % Hn;
    const bf16* qb = q + (size_t)bh * Tsz * Dh;
    const bf16* kb = k + (size_t)bh * Tsz * Dh;
    const bf16* vb = v + (size_t)bh * Tsz * Dh;
    char* KlB = (char*)&Kl[0][0];
    char* VtB = (char*)&Vt[0][0];
    char* PlB = (char*)&Pl[w][0][0];

    bf16x8 qa[2][2];
    #pragma unroll
    for (int fi = 0; fi < 2; ++fi) {
        int g = fi ? 15 - w : w;
        qa[fi][0] = *(const bf16x8*)&qb[(g * 16 + l4) * Dh + quad * 8];
        qa[fi][1] = *(const bf16x8*)&qb[(g * 16 + l4) * Dh + 32 + quad * 8];
    }

    #pragma unroll
    for (int it = 0; it < 4; ++it) {
        int c = it * 512 + tid;
        int row = c >> 3, ck = c & 7;
        bf16x8 kv = *(const bf16x8*)((const char*)kb + (size_t)c * 16);
        *(bf16x8*)(KlB + row * 128 + ((ck ^ (row & 7)) << 4)) = kv;
    }
    #pragma unroll
    for (int it = 0; it < 4; ++it) {
        int idx = it * 512 + tid;
        int s = idx & 63, g2 = idx >> 6;
        int d8 = (g2 & 7) * 8, sg = (g2 >> 3) * 64 + s;
        bf16x8 vv = *(const bf16x8*)&vb[(size_t)sg * Dh + d8];
        #pragma unroll
        for (int j = 0; j < 8; ++j) {
            int row = d8 + j;
            *(bf16*)(VtB + row * 512 + (((sg >> 3) ^ (row & 7)) << 4) + (sg & 7) * 2) = vv[j];
        }
    }
    __syncthreads();

    #pragma unroll
    for (int fi = 0; fi < 2; ++fi) {
        const int g = fi ? 15 - w : w;
        const int diag = g >> 2;
        const int tg = g * 16 + quad * 4;
        f32x4 o[4] = {f32x4{0,0,0,0}, f32x4{0,0,0,0}, f32x4{0,0,0,0}, f32x4{0,0,0,0}};
        float mrun[4] = {-3.0e38f, -3.0e38f, -3.0e38f, -3.0e38f};
        float lrun[4] = {0.f, 0.f, 0.f, 0.f};

        for (int kt = 0; kt <= diag; ++kt) {
            f32x4 sc[4] = {f32x4{0,0,0,0}, f32x4{0,0,0,0}, f32x4{0,0,0,0}, f32x4{0,0,0,0}};
            __builtin_amdgcn_s_setprio(1);
            #pragma unroll
            for (int nt = 0; nt < 4; ++nt) {
                const char* kbase = KlB + (kt * 64 + nt * 16 + l4) * 128;
                bf16x8 b0 = *(const bf16x8*)(kbase + ((quad ^ cswz) << 4));
                bf16x8 b1 = *(const bf16x8*)(kbase + (((4 + quad) ^ cswz) << 4));
                sc[nt] = MFMA16(qa[fi][0], b0, sc[nt]);
                sc[nt] = MFMA16(qa[fi][1], b1, sc[nt]);
            }
            __builtin_amdgcn_s_setprio(0);

            const bool isdiag = (kt == diag);
            float mnew[4], alpha[4];
            #pragma unroll
            for (int r = 0; r < 4; ++r) {
                float mx = mrun[r];
                #pragma unroll
                for (int nt = 0; nt < 4; ++nt) {
                    float sv = sc[nt][r] * SCL;
                    if (isdiag) {
                        int sg2 = kt * 64 + nt * 16 + l4;
                        if (sg2 > tg + r) sv = -1.0e30f;
                    }
                    sc[nt][r] = sv;
                    mx = fmaxf(mx, sv);
                }
                mx = redmax16(mx);
                mnew[r] = mx;
                alpha[r] = __builtin_amdgcn_exp2f(mrun[r] - mx);
                mrun[r] = mx;
            }
            #pragma unroll
            for (int r = 0; r < 4; ++r) {
                float sm = 0.f;
                #pragma unroll
                for (int nt = 0; nt < 4; ++nt) {
                    float e = __builtin_amdgcn_exp2f(sc[nt][r] - mnew[r]);
                    sc[nt][r] = e;
                    sm += e;
                }
                sm = redsum16(sm);
                lrun[r] = lrun[r] * alpha[r] + sm;
            }
            #pragma unroll
            for (int nt = 0; nt < 4; ++nt)
                #pragma unroll
                for (int r = 0; r < 4; ++r) o[nt][r] *= alpha[r];

            #pragma unroll
            for (int nt = 0; nt < 4; ++nt)
                #pragma unroll
                for (int r = 0; r < 4; ++r) {
                    int row = quad * 4 + r;
                    int colc = nt * 2 + (l4 >> 3);
                    *(bf16*)(PlB + row * 128 + ((colc ^ (row & 7)) << 4) + (l4 & 7) * 2)
                        = (bf16)sc[nt][r];
                }
            bf16x8 pa0 = *(const bf16x8*)(PlB + l4 * 128 + ((quad ^ cswz) << 4));
            bf16x8 pa1 = *(const bf16x8*)(PlB + l4 * 128 + (((4 + quad) ^ cswz) << 4));

            __builtin_amdgcn_s_setprio(1);
            #pragma unroll
            for (int nt = 0; nt < 4; ++nt) {
                const char* vbase = VtB + (nt * 16 + l4) * 512;
                bf16x8 v0 = *(const bf16x8*)(vbase + (((kt * 8 + quad) ^ cswz) << 4));
                bf16x8 v1 = *(const bf16x8*)(vbase + (((kt * 8 + 4 + quad) ^ cswz) << 4));
                o[nt] = MFMA16(pa0, v0, o[nt]);
                o[nt] = MFMA16(pa1, v1, o[nt]);
            }
            __builtin_amdgcn_s_setprio(0);
        }

        #pragma unroll
        for (int r = 0; r < 4; ++r) {
            float inv = 1.f / lrun[r];
            #pragma unroll
            for (int nt = 0; nt < 4; ++nt)
                att[((size_t)(b * Tsz + tg + r)) * Csz + h * Dh + nt * 16 + l4] =
                    (bf16)(o[nt][r] * inv);
        }
    }
}

extern "C" void kernel_launch(void* const* d_in, const int* in_sizes, int n_in,
                              void* d_out, int out_size, void* d_ws, size_t ws_size,
                              hipStream_t stream)
{
    const float* x  = (const float*)d_in[0];
    const float* Wq = (const float*)d_in[1];
    const float* Wk = (const float*)d_in[2];
    const float* Wv = (const float*)d_in[3];
    const float* Wp = (const float*)d_in[4];
    const float* bp = (const float*)d_in[5];
    float* out = (float*)d_out;

    const size_t npe = (size_t)Bsz * Tsz * Csz;   // 25,165,824 elems
    bf16* xb    = (bf16*)d_ws;          // [65536,384]; reused as att after qkv
    bf16* att   = xb;                   // alias: xb dead once qkv_gemm completes
    bf16* q     = xb + npe;             // [B,H,T,D]
    bf16* k     = q  + npe;
    bf16* v     = k  + npe;
    bf16* Btqkv = v  + npe;             // [1280,384] (pad rows zeroed)
    bf16* Bpt   = Btqkv + (size_t)NPAD * Csz;   // [512,384] (pad rows zeroed)

    convert_x<<<npe / 2048, 256, 0, stream>>>(x, xb);
    prep_w<<<NPAD + PPAD, 384, 0, stream>>>(Wq, Wk, Wv, Wp, Btqkv, Bpt);
    qkv_gemm<<<(Bsz * Tsz / 256) * (NPAD / 256), 512, 0, stream>>>(xb, Btqkv, q, k, v);
    attn_mfma<<<Bsz * Hn, 512, 0, stream>>>(q, k, v, att);
    proj_gemm<<<(Bsz * Tsz / 256) * (PPAD / 256), 512, 0, stream>>>(att, Bpt, bp, out);
}